// Round 4
// baseline (135.944 us; speedup 1.0000x reference)
//
#include <hip/hip_runtime.h>

#define BB 4
#define NN 2048
#define CC 128
#define KK 16

// fp32 element offsets within d_out
#define OFF_GF   ((size_t)BB * 3 * NN * KK)                 // grouped_features (B,256,N,K)
#define OFF_IDX  (OFF_GF + (size_t)BB * 2 * CC * NN * KK)   // idx_full (B,2,N,K)

__device__ __forceinline__ unsigned long long ordd(double d) {
    unsigned long long u = (unsigned long long)__double_as_longlong(d);
    return (u & 0x8000000000000000ull) ? ~u : (u | 0x8000000000000000ull);
}

// One wave (64 lanes) per query point. d2 computed in fp64 (exact products from
// fp32 inputs -> ordering matches the float64 numpy reference). Top-16 by
// (d2 asc, idx asc) via wave tournament on (key, idx) pairs.
__global__ __launch_bounds__(64) void knn_kernel(const float* __restrict__ pts,
                                                 float* __restrict__ out,
                                                 int* __restrict__ ws_idx) {
    const int blk = blockIdx.x;
    const int b = blk >> 11;
    const int n = blk & (NN - 1);
    const int lane = threadIdx.x;

    const float* __restrict__ P = pts + (size_t)b * 3 * NN;
    const double q0 = (double)P[n];
    const double q1 = (double)P[NN + n];
    const double q2 = (double)P[2 * NN + n];
    const double sqn = (q0 * q0 + q1 * q1) + q2 * q2;

    unsigned long long key[32];
#pragma unroll
    for (int i = 0; i < 32; ++i) {
        const int m = lane + (i << 6);
        const double m0 = (double)P[m];
        const double m1 = (double)P[NN + m];
        const double m2 = (double)P[2 * NN + m];
        const double sqm = (m0 * m0 + m1 * m1) + m2 * m2;
        const double inner = q0 * m0 + q1 * m1 + q2 * m2;   // exact products
        const double d2 = (sqn - 2.0 * inner) + sqm;
        key[i] = ordd(d2);
    }

    // per-lane min (key, slot): ascending i == ascending idx, strict < keeps lowest
    unsigned long long lk = key[0];
    unsigned li = 0;
#pragma unroll
    for (int i = 1; i < 32; ++i)
        if (key[i] < lk) { lk = key[i]; li = (unsigned)i; }

    unsigned myidx = 0;
    for (int r = 0; r < KK; ++r) {
        // wave-wide min on (key, idx) pairs
        unsigned long long bk = lk;
        unsigned bi = (unsigned)lane + (li << 6);
#pragma unroll
        for (int off = 32; off > 0; off >>= 1) {
            unsigned long long ok =
                (unsigned long long)__shfl_xor((long long)bk, off, 64);
            unsigned oi = (unsigned)__shfl_xor((int)bi, off, 64);
            if (ok < bk || (ok == bk && oi < bi)) { bk = ok; bi = oi; }
        }
        if (lane == r) myidx = bi;
        // remove winner (unique by idx); static indices only (no scratch)
        const unsigned wslot = bi >> 6;
        const bool mine = ((bi & 63u) == (unsigned)lane);
#pragma unroll
        for (int i = 0; i < 32; ++i)
            if (mine && (unsigned)i == wslot) key[i] = ~0ull;
        // recompute per-lane min
        lk = key[0]; li = 0;
#pragma unroll
        for (int i = 1; i < 32; ++i)
            if (key[i] < lk) { lk = key[i]; li = (unsigned)i; }
    }

    if (lane < KK) {
        const int k = lane;
        const size_t nk = (size_t)NN * KK;
        // grouped_points (B,3,N,K) fp32
        const size_t base0 = ((size_t)(b * 3) * NN + n) * KK + k;
        out[base0]          = P[myidx];
        out[base0 + nk]     = P[NN + myidx];
        out[base0 + 2 * nk] = P[2 * NN + myidx];
        // idx_full (B,2,N,K) fp32 (exact)
        const size_t base2 = ((size_t)(b * 2) * NN + n) * KK + k;
        out[OFF_IDX + base2]      = (float)b;
        out[OFF_IDX + base2 + nk] = (float)myidx;
        // exact indices for the gather kernel
        ws_idx[((size_t)b * NN + n) * KK + k] = (int)myidx;
    }
}

// One thread per (b,c,n): gather 16 features, write fp32 to rows c and c+128.
__global__ __launch_bounds__(256) void gather_feats(const float* __restrict__ pf,
                                                    const int* __restrict__ ws_idx,
                                                    float* __restrict__ out1) {
    const int t = blockIdx.x * 256 + threadIdx.x;   // B*C*N = 1,048,576
    const int n = t & (NN - 1);
    const int c = (t >> 11) & (CC - 1);
    const int b = t >> 18;

    const float* __restrict__ row = pf + ((size_t)b * CC + c) * NN;
    const int* __restrict__ ip = ws_idx + ((size_t)b * NN + n) * KK;

    int idx[KK];
#pragma unroll
    for (int k = 0; k < KK; ++k) idx[k] = ip[k];

    float4 f[4];
#pragma unroll
    for (int j = 0; j < 4; ++j) {
        f[j].x = row[idx[4 * j + 0]];
        f[j].y = row[idx[4 * j + 1]];
        f[j].z = row[idx[4 * j + 2]];
        f[j].w = row[idx[4 * j + 3]];
    }

    // grouped_features (B,256,N,K) fp32; duplicate at c and c+128
    const size_t base = (((size_t)b * (2 * CC) + c) * NN + n) * KK;
    float4* __restrict__ o = (float4*)(out1 + base);
    o[0] = f[0]; o[1] = f[1]; o[2] = f[2]; o[3] = f[3];
    float4* __restrict__ o2 = (float4*)(out1 + base + (size_t)CC * NN * KK);
    o2[0] = f[0]; o2[1] = f[1]; o2[2] = f[2]; o2[3] = f[3];
}

extern "C" void kernel_launch(void* const* d_in, const int* in_sizes, int n_in,
                              void* d_out, int out_size, void* d_ws, size_t ws_size,
                              hipStream_t stream) {
    (void)in_sizes; (void)n_in; (void)ws_size; (void)out_size;
    const float* pts = (const float*)d_in[0];
    const float* pf  = (const float*)d_in[1];
    float* out = (float*)d_out;
    int* ws_idx = (int*)d_ws;   // B*N*K int32 = 512 KB

    knn_kernel<<<BB * NN, 64, 0, stream>>>(pts, out, ws_idx);
    gather_feats<<<(BB * CC * NN) / 256, 256, 0, stream>>>(pf, ws_idx, out + OFF_GF);
}

// Round 5
// 115.407 us; speedup vs baseline: 1.1779x; 1.1779x over previous
//
#include <hip/hip_runtime.h>

#define BB 4
#define NN 2048
#define CC 128
#define KK 16
#define CAP 384

// fp32 element offsets within d_out
#define OFF_GF   ((size_t)BB * 3 * NN * KK)                 // grouped_features (B,256,N,K)
#define OFF_IDX  (OFF_GF + (size_t)BB * 2 * CC * NN * KK)   // idx_full (B,2,N,K)

__device__ __forceinline__ unsigned long long ordd(double d) {
    unsigned long long u = (unsigned long long)__double_as_longlong(d);
    return (u & 0x8000000000000000ull) ? ~u : (u | 0x8000000000000000ull);
}

// Deterministic fp64 d2 (explicit intrinsics: identical bits in both passes).
__device__ __forceinline__ double d2_eval(double q0, double q1, double q2, double sqn,
                                          double m0, double m1, double m2) {
    double sqm   = __fma_rn(m2, m2, __fma_rn(m1, m1, __dmul_rn(m0, m0)));
    double inner = __fma_rn(q2, m2, __fma_rn(q1, m1, __dmul_rn(q0, m0)));
    return __dadd_rn(__dsub_rn(sqn, __dadd_rn(inner, inner)), sqm);
}

// 4 waves/block, one query per wave. Exact fp64 top-16 via pivot + rank:
//  pass1: per-lane min key (no key array -> no spill)
//  pivot: wave-max of 16 group-of-4 mins  => >=16 candidates <= pivot
//  pass2: recompute keys, compact <=pivot to LDS (order-independent)
//  rank:  exact (key, idx) rank; rank<16 writes slot k=rank
__global__ __launch_bounds__(256) void knn_kernel(const float* __restrict__ pts,
                                                  float* __restrict__ out,
                                                  int* __restrict__ ws_idx) {
    __shared__ unsigned long long s_key[4][CAP];
    __shared__ unsigned s_sid[4][CAP];
    __shared__ int s_cnt[4];

    const int w = threadIdx.x >> 6;
    const int lane = threadIdx.x & 63;
    const int q = blockIdx.x * 4 + w;
    const int b = q >> 11;
    const int n = q & (NN - 1);

    if (lane == 0) s_cnt[w] = 0;   // same-wave DS ordering: visible to our atomics

    const float* __restrict__ P = pts + (size_t)b * 3 * NN;
    const double q0 = (double)P[n];
    const double q1 = (double)P[NN + n];
    const double q2 = (double)P[2 * NN + n];
    const double sqn = __fma_rn(q2, q2, __fma_rn(q1, q1, __dmul_rn(q0, q0)));

    // ---- pass 1: per-lane min key
    unsigned long long lmin = ~0ull;
#pragma unroll 8
    for (int i = 0; i < 32; ++i) {
        const int m = lane + (i << 6);
        const double m0 = (double)P[m];
        const double m1 = (double)P[NN + m];
        const double m2 = (double)P[2 * NN + m];
        const unsigned long long k = ordd(d2_eval(q0, q1, q2, sqn, m0, m1, m2));
        lmin = k < lmin ? k : lmin;
    }

    // ---- pivot
    unsigned long long g = lmin, o;
    o = (unsigned long long)__shfl_xor((long long)g, 1, 64);   g = o < g ? o : g;
    o = (unsigned long long)__shfl_xor((long long)g, 2, 64);   g = o < g ? o : g;
    unsigned long long piv = g;
    o = (unsigned long long)__shfl_xor((long long)piv, 4, 64);  piv = o > piv ? o : piv;
    o = (unsigned long long)__shfl_xor((long long)piv, 8, 64);  piv = o > piv ? o : piv;
    o = (unsigned long long)__shfl_xor((long long)piv, 16, 64); piv = o > piv ? o : piv;
    o = (unsigned long long)__shfl_xor((long long)piv, 32, 64); piv = o > piv ? o : piv;

    // ---- pass 2: recompute + compact
#pragma unroll 8
    for (int i = 0; i < 32; ++i) {
        const int m = lane + (i << 6);
        const double m0 = (double)P[m];
        const double m1 = (double)P[NN + m];
        const double m2 = (double)P[2 * NN + m];
        const unsigned long long k = ordd(d2_eval(q0, q1, q2, sqn, m0, m1, m2));
        if (k <= piv) {
            int pos = atomicAdd(&s_cnt[w], 1);
            if (pos < CAP) { s_key[w][pos] = k; s_sid[w][pos] = (unsigned)m; }
        }
    }
    __syncthreads();
    int C = s_cnt[w];
    if (C > CAP) C = CAP;

    // ---- rank & emit
    for (int base = 0; base < C; base += 64) {
        const int c = base + lane;
        const bool val = c < C;
        const unsigned long long mk = val ? s_key[w][c] : ~0ull;
        const unsigned mi = val ? s_sid[w][c] : 0xFFFFFFFFu;
        int rank = 0;
        for (int j = 0; j < C; ++j) {
            const unsigned long long kj = s_key[w][j];   // broadcast read
            const unsigned ij = s_sid[w][j];
            rank += (kj < mk || (kj == mk && ij < mi)) ? 1 : 0;
        }
        if (val && rank < KK) {
            const int k = rank;
            const unsigned myidx = mi;
            const size_t nk = (size_t)NN * KK;
            const size_t base0 = ((size_t)(b * 3) * NN + n) * KK + k;
            out[base0]            = P[myidx];
            out[base0 + nk]       = P[NN + myidx];
            out[base0 + 2 * nk]   = P[2 * NN + myidx];
            const size_t base2 = ((size_t)(b * 2) * NN + n) * KK + k;
            out[OFF_IDX + base2]      = (float)b;
            out[OFF_IDX + base2 + nk] = (float)myidx;
            ws_idx[((size_t)b * NN + n) * KK + k] = (int)myidx;
        }
    }
}

// One thread per (b,c,n): gather 16 features, write fp32 to rows c and c+128.
__global__ __launch_bounds__(256) void gather_feats(const float* __restrict__ pf,
                                                    const int* __restrict__ ws_idx,
                                                    float* __restrict__ out1) {
    const int t = blockIdx.x * 256 + threadIdx.x;   // B*C*N = 1,048,576
    const int n = t & (NN - 1);
    const int c = (t >> 11) & (CC - 1);
    const int b = t >> 18;

    const float* __restrict__ row = pf + ((size_t)b * CC + c) * NN;
    const int* __restrict__ ip = ws_idx + ((size_t)b * NN + n) * KK;

    int idx[KK];
#pragma unroll
    for (int k = 0; k < KK; ++k) idx[k] = ip[k];

    float4 f[4];
#pragma unroll
    for (int j = 0; j < 4; ++j) {
        f[j].x = row[idx[4 * j + 0]];
        f[j].y = row[idx[4 * j + 1]];
        f[j].z = row[idx[4 * j + 2]];
        f[j].w = row[idx[4 * j + 3]];
    }

    const size_t base = (((size_t)b * (2 * CC) + c) * NN + n) * KK;
    float4* __restrict__ o = (float4*)(out1 + base);
    o[0] = f[0]; o[1] = f[1]; o[2] = f[2]; o[3] = f[3];
    float4* __restrict__ o2 = (float4*)(out1 + base + (size_t)CC * NN * KK);
    o2[0] = f[0]; o2[1] = f[1]; o2[2] = f[2]; o2[3] = f[3];
}

extern "C" void kernel_launch(void* const* d_in, const int* in_sizes, int n_in,
                              void* d_out, int out_size, void* d_ws, size_t ws_size,
                              hipStream_t stream) {
    (void)in_sizes; (void)n_in; (void)ws_size; (void)out_size;
    const float* pts = (const float*)d_in[0];
    const float* pf  = (const float*)d_in[1];
    float* out = (float*)d_out;
    int* ws_idx = (int*)d_ws;   // B*N*K int32 = 512 KB

    knn_kernel<<<(BB * NN) / 4, 256, 0, stream>>>(pts, out, ws_idx);
    gather_feats<<<(BB * CC * NN) / 256, 256, 0, stream>>>(pf, ws_idx, out + OFF_GF);
}

// Round 6
// 97.934 us; speedup vs baseline: 1.3881x; 1.1784x over previous
//
#include <hip/hip_runtime.h>

#define BB 4
#define NN 2048
#define CC 128
#define KK 16
#define CAP 384

// fp32 element offsets within d_out
#define OFF_GF   ((size_t)BB * 3 * NN * KK)                 // grouped_features (B,256,N,K)
#define OFF_IDX  (OFF_GF + (size_t)BB * 2 * CC * NN * KK)   // idx_full (B,2,N,K)

__device__ __forceinline__ unsigned long long ordd(double d) {
    unsigned long long u = (unsigned long long)__double_as_longlong(d);
    return (u & 0x8000000000000000ull) ? ~u : (u | 0x8000000000000000ull);
}

// 4 waves/block, one query per wave.
//  phase A: fp32 screen, 32 keys in regs; pivot = max of 16 group-of-4 mins
//           (>=16 candidates guaranteed) + 2e-3 margin for fp32-vs-fp64 error
//  phase B: compact candidate ids to LDS (order-independent)
//  phase C: fp64 keys for candidates only (exact products from fp32 inputs)
//  phase D: exact (key, idx) rank; rank<16 emits slot k=rank
__global__ __launch_bounds__(256) void knn_kernel(const float* __restrict__ pts,
                                                  float* __restrict__ out,
                                                  int* __restrict__ ws_idx) {
    __shared__ unsigned long long s_key[4][CAP];
    __shared__ unsigned s_sid[4][CAP];
    __shared__ int s_cnt[4];

    const int w = threadIdx.x >> 6;
    const int lane = threadIdx.x & 63;
    const int q = blockIdx.x * 4 + w;
    const int b = q >> 11;
    const int n = q & (NN - 1);

    if (lane == 0) s_cnt[w] = 0;

    const float* __restrict__ P = pts + (size_t)b * 3 * NN;
    const float q0 = P[n], q1 = P[NN + n], q2 = P[2 * NN + n];
    const float sqnf = fmaf(q2, q2, fmaf(q1, q1, q0 * q0));

    // ---- phase A: fp32 screen
    float key[32];
#pragma unroll
    for (int i = 0; i < 32; ++i) {
        const int m = lane + (i << 6);
        const float m0 = P[m], m1 = P[NN + m], m2 = P[2 * NN + m];
        const float sqm = fmaf(m2, m2, fmaf(m1, m1, m0 * m0));
        const float inner = fmaf(q2, m2, fmaf(q1, m1, q0 * m0));
        key[i] = (sqnf - 2.0f * inner) + sqm;
    }
    float lmin = key[0];
#pragma unroll
    for (int i = 1; i < 32; ++i) lmin = key[i] < lmin ? key[i] : lmin;

    float g = lmin, o;
    o = __shfl_xor(g, 1, 64); g = o < g ? o : g;
    o = __shfl_xor(g, 2, 64); g = o < g ? o : g;      // min over group of 4 lanes
    float piv = g;
    o = __shfl_xor(piv, 4, 64);  piv = o > piv ? o : piv;
    o = __shfl_xor(piv, 8, 64);  piv = o > piv ? o : piv;
    o = __shfl_xor(piv, 16, 64); piv = o > piv ? o : piv;
    o = __shfl_xor(piv, 32, 64); piv = o > piv ? o : piv;  // max over 16 groups
    piv += 2e-3f;   // fp32 error margin (bound ~1e-4)

    // ---- phase B: compact candidate ids
#pragma unroll
    for (int i = 0; i < 32; ++i) {
        if (key[i] <= piv) {
            int pos = atomicAdd(&s_cnt[w], 1);
            if (pos < CAP) s_sid[w][pos] = (unsigned)(lane + (i << 6));
        }
    }
    __syncthreads();
    int C = s_cnt[w];
    if (C > CAP) C = CAP;

    // ---- phase C: fp64 keys for candidates only
    const double qd0 = (double)q0, qd1 = (double)q1, qd2 = (double)q2;
    const double sqnd = __fma_rn(qd2, qd2, __fma_rn(qd1, qd1, __dmul_rn(qd0, qd0)));
    for (int base = 0; base < C; base += 64) {
        const int c = base + lane;
        if (c < C) {
            const int m = (int)s_sid[w][c];
            const double m0 = (double)P[m], m1 = (double)P[NN + m], m2 = (double)P[2 * NN + m];
            const double sqm   = __fma_rn(m2, m2, __fma_rn(m1, m1, __dmul_rn(m0, m0)));
            const double inner = __fma_rn(qd2, m2, __fma_rn(qd1, m1, __dmul_rn(qd0, m0)));
            const double d2 = __dadd_rn(__dsub_rn(sqnd, __dadd_rn(inner, inner)), sqm);
            s_key[w][c] = ordd(d2);
        }
    }
    __syncthreads();

    // ---- phase D: rank & emit
    for (int base = 0; base < C; base += 64) {
        const int c = base + lane;
        const bool val = c < C;
        const unsigned long long mk = val ? s_key[w][c] : ~0ull;
        const unsigned mi = val ? s_sid[w][c] : 0xFFFFFFFFu;
        int rank = 0;
        for (int j = 0; j < C; ++j) {
            const unsigned long long kj = s_key[w][j];   // broadcast read
            const unsigned ij = s_sid[w][j];
            rank += (kj < mk || (kj == mk && ij < mi)) ? 1 : 0;
        }
        if (val && rank < KK) {
            const int k = rank;
            const unsigned myidx = mi;
            const size_t nk = (size_t)NN * KK;
            const size_t base0 = ((size_t)(b * 3) * NN + n) * KK + k;
            out[base0]            = P[myidx];
            out[base0 + nk]       = P[NN + myidx];
            out[base0 + 2 * nk]   = P[2 * NN + myidx];
            const size_t base2 = ((size_t)(b * 2) * NN + n) * KK + k;
            out[OFF_IDX + base2]      = (float)b;
            out[OFF_IDX + base2 + nk] = (float)myidx;
            ws_idx[((size_t)b * NN + n) * KK + k] = (int)myidx;
        }
    }
}

// Block = (b, c, 256-n tile). Stage the 8 KB feature row in LDS (coalesced),
// gather from LDS (random banks ~ conflict-free), coalesced float4 stores.
__global__ __launch_bounds__(256) void gather_feats(const float* __restrict__ pf,
                                                    const int* __restrict__ ws_idx,
                                                    float* __restrict__ out1) {
    __shared__ float s_row[NN];

    const int blk = blockIdx.x;          // B * C * 8 = 4096
    const int nt = blk & 7;
    const int c  = (blk >> 3) & (CC - 1);
    const int b  = blk >> 10;
    const int tid = threadIdx.x;
    const int n = nt * 256 + tid;

    const float* __restrict__ row = pf + ((size_t)b * CC + c) * NN;
    {
        const float4* __restrict__ r4 = (const float4*)row;
        float4 a0 = r4[tid];
        float4 a1 = r4[tid + 256];
        ((float4*)s_row)[tid]       = a0;
        ((float4*)s_row)[tid + 256] = a1;
    }
    __syncthreads();

    const int* __restrict__ ip = ws_idx + ((size_t)b * NN + n) * KK;
    const int4 i0 = ((const int4*)ip)[0];
    const int4 i1 = ((const int4*)ip)[1];
    const int4 i2 = ((const int4*)ip)[2];
    const int4 i3 = ((const int4*)ip)[3];

    float4 f0, f1, f2, f3;
    f0.x = s_row[i0.x]; f0.y = s_row[i0.y]; f0.z = s_row[i0.z]; f0.w = s_row[i0.w];
    f1.x = s_row[i1.x]; f1.y = s_row[i1.y]; f1.z = s_row[i1.z]; f1.w = s_row[i1.w];
    f2.x = s_row[i2.x]; f2.y = s_row[i2.y]; f2.z = s_row[i2.z]; f2.w = s_row[i2.w];
    f3.x = s_row[i3.x]; f3.y = s_row[i3.y]; f3.z = s_row[i3.z]; f3.w = s_row[i3.w];

    // grouped_features (B,256,N,K); duplicate at c and c+128
    const size_t base = (((size_t)b * (2 * CC) + c) * NN + n) * KK;
    float4* __restrict__ o = (float4*)(out1 + base);
    o[0] = f0; o[1] = f1; o[2] = f2; o[3] = f3;
    float4* __restrict__ o2 = (float4*)(out1 + base + (size_t)CC * NN * KK);
    o2[0] = f0; o2[1] = f1; o2[2] = f2; o2[3] = f3;
}

extern "C" void kernel_launch(void* const* d_in, const int* in_sizes, int n_in,
                              void* d_out, int out_size, void* d_ws, size_t ws_size,
                              hipStream_t stream) {
    (void)in_sizes; (void)n_in; (void)ws_size; (void)out_size;
    const float* pts = (const float*)d_in[0];
    const float* pf  = (const float*)d_in[1];
    float* out = (float*)d_out;
    int* ws_idx = (int*)d_ws;   // B*N*K int32 = 512 KB

    knn_kernel<<<(BB * NN) / 4, 256, 0, stream>>>(pts, out, ws_idx);
    gather_feats<<<BB * CC * 8, 256, 0, stream>>>(pf, ws_idx, out + OFF_GF);
}

// Round 7
// 73.612 us; speedup vs baseline: 1.8468x; 1.3304x over previous
//
#include <hip/hip_runtime.h>

#define BB 4
#define NN 2048
#define CC 128
#define KK 16
#define CAP 256   // fallback candidate capacity (common case C ~ 20)

// fp32 element offsets within d_out
#define OFF_GF   ((size_t)BB * 3 * NN * KK)                 // grouped_features (B,256,N,K)
#define OFF_IDX  (OFF_GF + (size_t)BB * 2 * CC * NN * KK)   // idx_full (B,2,N,K)

__device__ __forceinline__ unsigned long long ordd(double d) {
    unsigned long long u = (unsigned long long)__double_as_longlong(d);
    return (u & 0x8000000000000000ull) ? ~u : (u | 0x8000000000000000ull);
}

__device__ __forceinline__ void emit_one(const float* __restrict__ P,
                                         float* __restrict__ out,
                                         int* __restrict__ ws_idx,
                                         int b, int n, int k, unsigned myidx) {
    const size_t nk = (size_t)NN * KK;
    const size_t base0 = ((size_t)(b * 3) * NN + n) * KK + k;
    out[base0]            = P[myidx];
    out[base0 + nk]       = P[NN + myidx];
    out[base0 + 2 * nk]   = P[2 * NN + myidx];
    const size_t base2 = ((size_t)(b * 2) * NN + n) * KK + k;
    out[OFF_IDX + base2]      = (float)b;
    out[OFF_IDX + base2 + nk] = (float)myidx;
    ws_idx[((size_t)b * NN + n) * KK + k] = (int)myidx;
}

// 4 waves/block, one query per wave. No per-thread arrays (no spill), no
// atomics, no O(C^2) rank in the common path.
//  pass1: per-lane fp32 min
//  pivot: 16th-smallest of the 64 lane-mins (register bitonic) + margin
//  pass2: recompute, ballot-prefix compact candidate ids -> LDS
//  C<=64: fp64 keys in lanes, bitonic sort 64 (key,idx) pairs, lanes 0..15 emit
//  C>64 (≈never): exact rank with recomputed fp64 keys
__global__ __launch_bounds__(256) void knn_kernel(const float* __restrict__ pts,
                                                  float* __restrict__ out,
                                                  int* __restrict__ ws_idx) {
    __shared__ unsigned s_sid[4][CAP];

    const int w = threadIdx.x >> 6;
    const int lane = threadIdx.x & 63;
    const int q = blockIdx.x * 4 + w;
    const int b = q >> 11;
    const int n = q & (NN - 1);

    const float* __restrict__ P = pts + (size_t)b * 3 * NN;
    const float q0 = P[n], q1 = P[NN + n], q2 = P[2 * NN + n];
    const float sqn = fmaf(q2, q2, fmaf(q1, q1, q0 * q0));

    // ---- pass 1: per-lane min (single live scalar)
    float lmin = 1e30f;
#pragma unroll
    for (int i = 0; i < 32; ++i) {
        const int m = lane + (i << 6);
        const float m0 = P[m], m1 = P[NN + m], m2 = P[2 * NN + m];
        const float sqm = fmaf(m2, m2, fmaf(m1, m1, m0 * m0));
        const float inner = fmaf(q2, m2, fmaf(q1, m1, q0 * m0));
        const float d2 = (sqn - 2.0f * inner) + sqm;
        lmin = d2 < lmin ? d2 : lmin;
    }

    // ---- pivot: bitonic-sort the 64 lane-mins, take 16th smallest
    {
        float v = lmin;
#pragma unroll
        for (int k = 2; k <= 64; k <<= 1) {
#pragma unroll
            for (int j = k >> 1; j > 0; j >>= 1) {
                const float o = __shfl_xor(v, j, 64);
                const bool up = ((lane & k) == 0);
                const bool iAmLow = ((lane & j) == 0);
                const bool keepOther = (iAmLow == up) ? (o < v) : (o > v);
                v = keepOther ? o : v;
            }
        }
        lmin = __shfl(v, 15, 64);   // reuse lmin as pivot carrier
    }
    const float piv = lmin + 2e-3f;   // fp32-vs-fp64 containment margin (~20x bound)

    // ---- pass 2: recompute keys, ballot-prefix compaction
    const unsigned long long below = (1ull << lane) - 1ull;
    unsigned tot = 0;
#pragma unroll
    for (int i = 0; i < 32; ++i) {
        const int m = lane + (i << 6);
        const float m0 = P[m], m1 = P[NN + m], m2 = P[2 * NN + m];
        const float sqm = fmaf(m2, m2, fmaf(m1, m1, m0 * m0));
        const float inner = fmaf(q2, m2, fmaf(q1, m1, q0 * m0));
        const float d2 = (sqn - 2.0f * inner) + sqm;
        const bool cand = (d2 <= piv);
        const unsigned long long mask = __ballot(cand);
        if (cand) {
            const unsigned pos = tot + (unsigned)__popcll(mask & below);
            if (pos < CAP) s_sid[w][pos] = (unsigned)m;
        }
        tot += (unsigned)__popcll(mask);
    }
    const int C = (int)(tot < CAP ? tot : CAP);
    __syncthreads();   // order LDS writes before reads (uniform: all waves reach)

    const double qd0 = (double)q0, qd1 = (double)q1, qd2 = (double)q2;
    const double sqnd = __fma_rn(qd2, qd2, __fma_rn(qd1, qd1, __dmul_rn(qd0, qd0)));

    if (C <= 64) {
        // candidate per lane; fp64 exact key
        unsigned long long key = ~0ull;
        unsigned idx = 0xFFFFFFFFu;
        if (lane < C) {
            const int m = (int)s_sid[w][lane];
            const double m0 = (double)P[m], m1 = (double)P[NN + m], m2 = (double)P[2 * NN + m];
            const double sqm   = __fma_rn(m2, m2, __fma_rn(m1, m1, __dmul_rn(m0, m0)));
            const double inner = __fma_rn(qd2, m2, __fma_rn(qd1, m1, __dmul_rn(qd0, m0)));
            const double d2 = __dadd_rn(__dsub_rn(sqnd, __dadd_rn(inner, inner)), sqm);
            key = ordd(d2);
            idx = (unsigned)m;
        }
        // bitonic sort 64 (key, idx) pairs ascending
#pragma unroll
        for (int k = 2; k <= 64; k <<= 1) {
#pragma unroll
            for (int j = k >> 1; j > 0; j >>= 1) {
                const unsigned long long ok =
                    (unsigned long long)__shfl_xor((long long)key, j, 64);
                const unsigned oi = (unsigned)__shfl_xor((int)idx, j, 64);
                const bool up = ((lane & k) == 0);
                const bool iAmLow = ((lane & j) == 0);
                const bool oLess = (ok < key) || (ok == key && oi < idx);
                const bool keepOther = (iAmLow == up) ? oLess : !oLess;
                if (keepOther) { key = ok; idx = oi; }
            }
        }
        if (lane < KK) emit_one(P, out, ws_idx, b, n, lane, idx);
    } else {
        // rare exact fallback: rank via recomputed fp64 keys (ids pre-barrier)
        for (int cb = 0; cb < C; cb += 64) {
            const int c = cb + lane;
            unsigned long long mk = ~0ull;
            unsigned mi = 0xFFFFFFFFu;
            if (c < C) {
                const int m = (int)s_sid[w][c];
                const double m0 = (double)P[m], m1 = (double)P[NN + m], m2 = (double)P[2 * NN + m];
                const double sqm   = __fma_rn(m2, m2, __fma_rn(m1, m1, __dmul_rn(m0, m0)));
                const double inner = __fma_rn(qd2, m2, __fma_rn(qd1, m1, __dmul_rn(qd0, m0)));
                mk = ordd(__dadd_rn(__dsub_rn(sqnd, __dadd_rn(inner, inner)), sqm));
                mi = (unsigned)m;
            }
            int rank = 0;
            for (int j = 0; j < C; ++j) {
                const int mj = (int)s_sid[w][j];    // broadcast read
                const double m0 = (double)P[mj], m1 = (double)P[NN + mj], m2 = (double)P[2 * NN + mj];
                const double sqm   = __fma_rn(m2, m2, __fma_rn(m1, m1, __dmul_rn(m0, m0)));
                const double inner = __fma_rn(qd2, m2, __fma_rn(qd1, m1, __dmul_rn(qd0, m0)));
                const unsigned long long kj =
                    ordd(__dadd_rn(__dsub_rn(sqnd, __dadd_rn(inner, inner)), sqm));
                rank += (kj < mk || (kj == mk && (unsigned)mj < mi)) ? 1 : 0;
            }
            if (c < C && rank < KK) emit_one(P, out, ws_idx, b, n, rank, mi);
        }
    }
}

// Block = (b, c, 256-n tile). Stage the 8 KB feature row in LDS (coalesced),
// gather from LDS, coalesced float4 stores. (UNCHANGED from round 6.)
__global__ __launch_bounds__(256) void gather_feats(const float* __restrict__ pf,
                                                    const int* __restrict__ ws_idx,
                                                    float* __restrict__ out1) {
    __shared__ float s_row[NN];

    const int blk = blockIdx.x;          // B * C * 8 = 4096
    const int nt = blk & 7;
    const int c  = (blk >> 3) & (CC - 1);
    const int b  = blk >> 10;
    const int tid = threadIdx.x;
    const int n = nt * 256 + tid;

    const float* __restrict__ row = pf + ((size_t)b * CC + c) * NN;
    {
        const float4* __restrict__ r4 = (const float4*)row;
        float4 a0 = r4[tid];
        float4 a1 = r4[tid + 256];
        ((float4*)s_row)[tid]       = a0;
        ((float4*)s_row)[tid + 256] = a1;
    }
    __syncthreads();

    const int* __restrict__ ip = ws_idx + ((size_t)b * NN + n) * KK;
    const int4 i0 = ((const int4*)ip)[0];
    const int4 i1 = ((const int4*)ip)[1];
    const int4 i2 = ((const int4*)ip)[2];
    const int4 i3 = ((const int4*)ip)[3];

    float4 f0, f1, f2, f3;
    f0.x = s_row[i0.x]; f0.y = s_row[i0.y]; f0.z = s_row[i0.z]; f0.w = s_row[i0.w];
    f1.x = s_row[i1.x]; f1.y = s_row[i1.y]; f1.z = s_row[i1.z]; f1.w = s_row[i1.w];
    f2.x = s_row[i2.x]; f2.y = s_row[i2.y]; f2.z = s_row[i2.z]; f2.w = s_row[i2.w];
    f3.x = s_row[i3.x]; f3.y = s_row[i3.y]; f3.z = s_row[i3.z]; f3.w = s_row[i3.w];

    // grouped_features (B,256,N,K); duplicate at c and c+128
    const size_t base = (((size_t)b * (2 * CC) + c) * NN + n) * KK;
    float4* __restrict__ o = (float4*)(out1 + base);
    o[0] = f0; o[1] = f1; o[2] = f2; o[3] = f3;
    float4* __restrict__ o2 = (float4*)(out1 + base + (size_t)CC * NN * KK);
    o2[0] = f0; o2[1] = f1; o2[2] = f2; o2[3] = f3;
}

extern "C" void kernel_launch(void* const* d_in, const int* in_sizes, int n_in,
                              void* d_out, int out_size, void* d_ws, size_t ws_size,
                              hipStream_t stream) {
    (void)in_sizes; (void)n_in; (void)ws_size; (void)out_size;
    const float* pts = (const float*)d_in[0];
    const float* pf  = (const float*)d_in[1];
    float* out = (float*)d_out;
    int* ws_idx = (int*)d_ws;   // B*N*K int32 = 512 KB

    knn_kernel<<<(BB * NN) / 4, 256, 0, stream>>>(pts, out, ws_idx);
    gather_feats<<<BB * CC * 8, 256, 0, stream>>>(pf, ws_idx, out + OFF_GF);
}

// Round 9
// 53.744 us; speedup vs baseline: 2.5295x; 1.3697x over previous
//
#include <hip/hip_runtime.h>

#define BB 4
#define NN 2048
#define CC 128
#define KK 16
#define CAP 256   // fallback candidate capacity (common case C ~ 20)

typedef float f32x4 __attribute__((ext_vector_type(4)));

// fp32 element offsets within d_out
#define OFF_GF   ((size_t)BB * 3 * NN * KK)                 // grouped_features (B,256,N,K)
#define OFF_IDX  (OFF_GF + (size_t)BB * 2 * CC * NN * KK)   // idx_full (B,2,N,K)

__device__ __forceinline__ unsigned long long ordd(double d) {
    unsigned long long u = (unsigned long long)__double_as_longlong(d);
    return (u & 0x8000000000000000ull) ? ~u : (u | 0x8000000000000000ull);
}

__device__ __forceinline__ void emit_one(const float* __restrict__ P,
                                         float* __restrict__ out,
                                         int* __restrict__ ws_idx,
                                         int b, int n, int k, unsigned myidx) {
    const size_t nk = (size_t)NN * KK;
    const size_t base0 = ((size_t)(b * 3) * NN + n) * KK + k;
    out[base0]            = P[myidx];
    out[base0 + nk]       = P[NN + myidx];
    out[base0 + 2 * nk]   = P[2 * NN + myidx];
    const size_t base2 = ((size_t)(b * 2) * NN + n) * KK + k;
    out[OFF_IDX + base2]      = (float)b;
    out[OFF_IDX + base2 + nk] = (float)myidx;
    ws_idx[((size_t)b * NN + n) * KK + k] = (int)myidx;
}

// ==== knn: UNCHANGED from round 7 (isolates this round's gather delta) ====
__global__ __launch_bounds__(256) void knn_kernel(const float* __restrict__ pts,
                                                  float* __restrict__ out,
                                                  int* __restrict__ ws_idx) {
    __shared__ unsigned s_sid[4][CAP];

    const int w = threadIdx.x >> 6;
    const int lane = threadIdx.x & 63;
    const int q = blockIdx.x * 4 + w;
    const int b = q >> 11;
    const int n = q & (NN - 1);

    const float* __restrict__ P = pts + (size_t)b * 3 * NN;
    const float q0 = P[n], q1 = P[NN + n], q2 = P[2 * NN + n];
    const float sqn = fmaf(q2, q2, fmaf(q1, q1, q0 * q0));

    // ---- pass 1: per-lane min (single live scalar)
    float lmin = 1e30f;
#pragma unroll
    for (int i = 0; i < 32; ++i) {
        const int m = lane + (i << 6);
        const float m0 = P[m], m1 = P[NN + m], m2 = P[2 * NN + m];
        const float sqm = fmaf(m2, m2, fmaf(m1, m1, m0 * m0));
        const float inner = fmaf(q2, m2, fmaf(q1, m1, q0 * m0));
        const float d2 = (sqn - 2.0f * inner) + sqm;
        lmin = d2 < lmin ? d2 : lmin;
    }

    // ---- pivot: bitonic-sort the 64 lane-mins, take 16th smallest
    {
        float v = lmin;
#pragma unroll
        for (int k = 2; k <= 64; k <<= 1) {
#pragma unroll
            for (int j = k >> 1; j > 0; j >>= 1) {
                const float o = __shfl_xor(v, j, 64);
                const bool up = ((lane & k) == 0);
                const bool iAmLow = ((lane & j) == 0);
                const bool keepOther = (iAmLow == up) ? (o < v) : (o > v);
                v = keepOther ? o : v;
            }
        }
        lmin = __shfl(v, 15, 64);
    }
    const float piv = lmin + 2e-3f;

    // ---- pass 2: recompute keys, ballot-prefix compaction
    const unsigned long long below = (1ull << lane) - 1ull;
    unsigned tot = 0;
#pragma unroll
    for (int i = 0; i < 32; ++i) {
        const int m = lane + (i << 6);
        const float m0 = P[m], m1 = P[NN + m], m2 = P[2 * NN + m];
        const float sqm = fmaf(m2, m2, fmaf(m1, m1, m0 * m0));
        const float inner = fmaf(q2, m2, fmaf(q1, m1, q0 * m0));
        const float d2 = (sqn - 2.0f * inner) + sqm;
        const bool cand = (d2 <= piv);
        const unsigned long long mask = __ballot(cand);
        if (cand) {
            const unsigned pos = tot + (unsigned)__popcll(mask & below);
            if (pos < CAP) s_sid[w][pos] = (unsigned)m;
        }
        tot += (unsigned)__popcll(mask);
    }
    const int C = (int)(tot < CAP ? tot : CAP);
    __syncthreads();

    const double qd0 = (double)q0, qd1 = (double)q1, qd2 = (double)q2;
    const double sqnd = __fma_rn(qd2, qd2, __fma_rn(qd1, qd1, __dmul_rn(qd0, qd0)));

    if (C <= 64) {
        unsigned long long key = ~0ull;
        unsigned idx = 0xFFFFFFFFu;
        if (lane < C) {
            const int m = (int)s_sid[w][lane];
            const double m0 = (double)P[m], m1 = (double)P[NN + m], m2 = (double)P[2 * NN + m];
            const double sqm   = __fma_rn(m2, m2, __fma_rn(m1, m1, __dmul_rn(m0, m0)));
            const double inner = __fma_rn(qd2, m2, __fma_rn(qd1, m1, __dmul_rn(qd0, m0)));
            const double d2 = __dadd_rn(__dsub_rn(sqnd, __dadd_rn(inner, inner)), sqm);
            key = ordd(d2);
            idx = (unsigned)m;
        }
#pragma unroll
        for (int k = 2; k <= 64; k <<= 1) {
#pragma unroll
            for (int j = k >> 1; j > 0; j >>= 1) {
                const unsigned long long ok =
                    (unsigned long long)__shfl_xor((long long)key, j, 64);
                const unsigned oi = (unsigned)__shfl_xor((int)idx, j, 64);
                const bool up = ((lane & k) == 0);
                const bool iAmLow = ((lane & j) == 0);
                const bool oLess = (ok < key) || (ok == key && oi < idx);
                const bool keepOther = (iAmLow == up) ? oLess : !oLess;
                if (keepOther) { key = ok; idx = oi; }
            }
        }
        if (lane < KK) emit_one(P, out, ws_idx, b, n, lane, idx);
    } else {
        for (int cb = 0; cb < C; cb += 64) {
            const int c = cb + lane;
            unsigned long long mk = ~0ull;
            unsigned mi = 0xFFFFFFFFu;
            if (c < C) {
                const int m = (int)s_sid[w][c];
                const double m0 = (double)P[m], m1 = (double)P[NN + m], m2 = (double)P[2 * NN + m];
                const double sqm   = __fma_rn(m2, m2, __fma_rn(m1, m1, __dmul_rn(m0, m0)));
                const double inner = __fma_rn(qd2, m2, __fma_rn(qd1, m1, __dmul_rn(qd0, m0)));
                mk = ordd(__dadd_rn(__dsub_rn(sqnd, __dadd_rn(inner, inner)), sqm));
                mi = (unsigned)m;
            }
            int rank = 0;
            for (int j = 0; j < C; ++j) {
                const int mj = (int)s_sid[w][j];
                const double m0 = (double)P[mj], m1 = (double)P[NN + mj], m2 = (double)P[2 * NN + mj];
                const double sqm   = __fma_rn(m2, m2, __fma_rn(m1, m1, __dmul_rn(m0, m0)));
                const double inner = __fma_rn(qd2, m2, __fma_rn(qd1, m1, __dmul_rn(qd0, m0)));
                const unsigned long long kj =
                    ordd(__dadd_rn(__dsub_rn(sqnd, __dadd_rn(inner, inner)), sqm));
                rank += (kj < mk || (kj == mk && (unsigned)mj < mi)) ? 1 : 0;
            }
            if (c < C && rank < KK) emit_one(P, out, ws_idx, b, n, rank, mi);
        }
    }
}

// ==== gather v3: dense per-instruction store footprint ====
// Block = (b, c, 256-n tile). Thread t owns (n_sub = t>>2, quarter = t&3):
// one wave instruction covers 16 n x 4 quarters = 1 KB fully contiguous
// (16 full-line requests instead of 64 partial-line). NT stores (write-once).
__global__ __launch_bounds__(256) void gather_feats(const float* __restrict__ pf,
                                                    const int* __restrict__ ws_idx,
                                                    float* __restrict__ out1) {
    __shared__ float s_row[NN];

    const int blk = blockIdx.x;          // B * C * 8 = 4096
    const int nt = blk & 7;
    const int c  = (blk >> 3) & (CC - 1);
    const int b  = blk >> 10;
    const int tid = threadIdx.x;

    const float* __restrict__ row = pf + ((size_t)b * CC + c) * NN;
    {
        const f32x4* __restrict__ r4 = (const f32x4*)row;
        f32x4 a0 = r4[tid];
        f32x4 a1 = r4[tid + 256];
        ((f32x4*)s_row)[tid]       = a0;
        ((f32x4*)s_row)[tid + 256] = a1;
    }
    __syncthreads();

    const size_t cbase  = ((size_t)b * (2 * CC) + c) * NN * KK;   // (b,c,0,0)
    const size_t cbase2 = cbase + (size_t)CC * NN * KK;           // dup at c+128
    const int4* __restrict__ ibase =
        (const int4*)(ws_idx + (size_t)b * NN * KK);              // 4 int4 per n

#pragma unroll
    for (int task = 0; task < 4; ++task) {
        const int gid = task * 256 + tid;          // 0..1023 within tile
        const int n_sub = gid >> 2;
        const int qq = gid & 3;
        const int n = nt * 256 + n_sub;

        const int4 iv = ibase[n * 4 + qq];         // dense 1 KB/wave
        f32x4 f;
        f.x = s_row[iv.x]; f.y = s_row[iv.y]; f.z = s_row[iv.z]; f.w = s_row[iv.w];

        const size_t off = (size_t)n * KK + qq * 4;
        __builtin_nontemporal_store(f, (f32x4*)(out1 + cbase + off));
        __builtin_nontemporal_store(f, (f32x4*)(out1 + cbase2 + off));
    }
}

extern "C" void kernel_launch(void* const* d_in, const int* in_sizes, int n_in,
                              void* d_out, int out_size, void* d_ws, size_t ws_size,
                              hipStream_t stream) {
    (void)in_sizes; (void)n_in; (void)ws_size; (void)out_size;
    const float* pts = (const float*)d_in[0];
    const float* pf  = (const float*)d_in[1];
    float* out = (float*)d_out;
    int* ws_idx = (int*)d_ws;   // B*N*K int32 = 512 KB

    knn_kernel<<<(BB * NN) / 4, 256, 0, stream>>>(pts, out, ws_idx);
    gather_feats<<<BB * CC * 8, 256, 0, stream>>>(pf, ws_idx, out + OFF_GF);
}

// Round 10
// 51.544 us; speedup vs baseline: 2.6374x; 1.0427x over previous
//
#include <hip/hip_runtime.h>

#define BB 4
#define NN 2048
#define CC 128
#define KK 16
#define CAP 256   // fallback candidate capacity (common case C ~ 20)

typedef float f32x4 __attribute__((ext_vector_type(4)));

// fp32 element offsets within d_out
#define OFF_GF   ((size_t)BB * 3 * NN * KK)                 // grouped_features (B,256,N,K)
#define OFF_IDX  (OFF_GF + (size_t)BB * 2 * CC * NN * KK)   // idx_full (B,2,N,K)

__device__ __forceinline__ unsigned long long ordd(double d) {
    unsigned long long u = (unsigned long long)__double_as_longlong(d);
    return (u & 0x8000000000000000ull) ? ~u : (u | 0x8000000000000000ull);
}

__device__ __forceinline__ void emit_one(const float* __restrict__ P,
                                         float* __restrict__ out,
                                         int* __restrict__ ws_idx,
                                         int b, int n, int k, unsigned myidx) {
    const size_t nk = (size_t)NN * KK;
    const size_t base0 = ((size_t)(b * 3) * NN + n) * KK + k;
    out[base0]            = P[myidx];
    out[base0 + nk]       = P[NN + myidx];
    out[base0 + 2 * nk]   = P[2 * NN + myidx];
    const size_t base2 = ((size_t)(b * 2) * NN + n) * KK + k;
    out[OFF_IDX + base2]      = (float)b;
    out[OFF_IDX + base2 + nk] = (float)myidx;
    ws_idx[((size_t)b * NN + n) * KK + k] = (int)myidx;
}

// 4 waves/block, one query per wave. fp32 screen with f32x4-vectorized loads
// (4 candidates/lane/iter; d2 expression per candidate identical to r7).
__global__ __launch_bounds__(256) void knn_kernel(const float* __restrict__ pts,
                                                  float* __restrict__ out,
                                                  int* __restrict__ ws_idx) {
    __shared__ unsigned s_sid[4][CAP];

    const int w = threadIdx.x >> 6;
    const int lane = threadIdx.x & 63;
    const int q = blockIdx.x * 4 + w;
    const int b = q >> 11;
    const int n = q & (NN - 1);

    const float* __restrict__ P = pts + (size_t)b * 3 * NN;
    const f32x4* __restrict__ Px = (const f32x4*)P;
    const f32x4* __restrict__ Py = (const f32x4*)(P + NN);
    const f32x4* __restrict__ Pz = (const f32x4*)(P + 2 * NN);

    const float q0 = P[n], q1 = P[NN + n], q2 = P[2 * NN + n];
    const float sqn = fmaf(q2, q2, fmaf(q1, q1, q0 * q0));

    // ---- pass 1: per-lane min, 4 candidates per iter (4 independent chains)
    float l0 = 1e30f, l1 = 1e30f, l2 = 1e30f, l3 = 1e30f;
#pragma unroll
    for (int i = 0; i < 8; ++i) {
        const int v = i * 64 + lane;                  // float4 index
        const f32x4 mx = Px[v], my = Py[v], mz = Pz[v];
#define D2F(j) (sqn - 2.0f * fmaf(q2, mz[j], fmaf(q1, my[j], q0 * mx[j]))) \
               + fmaf(mz[j], mz[j], fmaf(my[j], my[j], mx[j] * mx[j]))
        const float d0 = D2F(0), d1 = D2F(1), d2v = D2F(2), d3 = D2F(3);
        l0 = d0 < l0 ? d0 : l0;
        l1 = d1 < l1 ? d1 : l1;
        l2 = d2v < l2 ? d2v : l2;
        l3 = d3 < l3 ? d3 : l3;
    }
    float lmin = l0 < l1 ? l0 : l1;
    lmin = l2 < lmin ? l2 : lmin;
    lmin = l3 < lmin ? l3 : lmin;

    // ---- pivot: bitonic-sort the 64 lane-mins, take 16th smallest
    {
        float v = lmin;
#pragma unroll
        for (int k = 2; k <= 64; k <<= 1) {
#pragma unroll
            for (int j = k >> 1; j > 0; j >>= 1) {
                const float o = __shfl_xor(v, j, 64);
                const bool up = ((lane & k) == 0);
                const bool iAmLow = ((lane & j) == 0);
                const bool keepOther = (iAmLow == up) ? (o < v) : (o > v);
                v = keepOther ? o : v;
            }
        }
        lmin = __shfl(v, 15, 64);
    }
    const float piv = lmin + 2e-3f;   // fp32-vs-fp64 containment margin

    // ---- pass 2: recompute (vectorized), ballot-prefix compaction
    const unsigned long long below = (1ull << lane) - 1ull;
    unsigned tot = 0;
#pragma unroll
    for (int i = 0; i < 8; ++i) {
        const int v = i * 64 + lane;
        const f32x4 mx = Px[v], my = Py[v], mz = Pz[v];
        const float dv[4] = { D2F(0), D2F(1), D2F(2), D2F(3) };
#pragma unroll
        for (int j = 0; j < 4; ++j) {
            const bool cand = (dv[j] <= piv);
            const unsigned long long mask = __ballot(cand);
            if (cand) {
                const unsigned pos = tot + (unsigned)__popcll(mask & below);
                if (pos < CAP) s_sid[w][pos] = (unsigned)(4 * v + j);
            }
            tot += (unsigned)__popcll(mask);
        }
    }
#undef D2F
    const int C = (int)(tot < CAP ? tot : CAP);
    __syncthreads();

    const double qd0 = (double)q0, qd1 = (double)q1, qd2 = (double)q2;
    const double sqnd = __fma_rn(qd2, qd2, __fma_rn(qd1, qd1, __dmul_rn(qd0, qd0)));

    if (C <= 64) {
        unsigned long long key = ~0ull;
        unsigned idx = 0xFFFFFFFFu;
        if (lane < C) {
            const int m = (int)s_sid[w][lane];
            const double m0 = (double)P[m], m1 = (double)P[NN + m], m2 = (double)P[2 * NN + m];
            const double sqm   = __fma_rn(m2, m2, __fma_rn(m1, m1, __dmul_rn(m0, m0)));
            const double inner = __fma_rn(qd2, m2, __fma_rn(qd1, m1, __dmul_rn(qd0, m0)));
            const double d2 = __dadd_rn(__dsub_rn(sqnd, __dadd_rn(inner, inner)), sqm);
            key = ordd(d2);
            idx = (unsigned)m;
        }
#pragma unroll
        for (int k = 2; k <= 64; k <<= 1) {
#pragma unroll
            for (int j = k >> 1; j > 0; j >>= 1) {
                const unsigned long long ok =
                    (unsigned long long)__shfl_xor((long long)key, j, 64);
                const unsigned oi = (unsigned)__shfl_xor((int)idx, j, 64);
                const bool up = ((lane & k) == 0);
                const bool iAmLow = ((lane & j) == 0);
                const bool oLess = (ok < key) || (ok == key && oi < idx);
                const bool keepOther = (iAmLow == up) ? oLess : !oLess;
                if (keepOther) { key = ok; idx = oi; }
            }
        }
        if (lane < KK) emit_one(P, out, ws_idx, b, n, lane, idx);
    } else {
        for (int cb = 0; cb < C; cb += 64) {
            const int c = cb + lane;
            unsigned long long mk = ~0ull;
            unsigned mi = 0xFFFFFFFFu;
            if (c < C) {
                const int m = (int)s_sid[w][c];
                const double m0 = (double)P[m], m1 = (double)P[NN + m], m2 = (double)P[2 * NN + m];
                const double sqm   = __fma_rn(m2, m2, __fma_rn(m1, m1, __dmul_rn(m0, m0)));
                const double inner = __fma_rn(qd2, m2, __fma_rn(qd1, m1, __dmul_rn(qd0, m0)));
                mk = ordd(__dadd_rn(__dsub_rn(sqnd, __dadd_rn(inner, inner)), sqm));
                mi = (unsigned)m;
            }
            int rank = 0;
            for (int j = 0; j < C; ++j) {
                const int mj = (int)s_sid[w][j];
                const double m0 = (double)P[mj], m1 = (double)P[NN + mj], m2 = (double)P[2 * NN + mj];
                const double sqm   = __fma_rn(m2, m2, __fma_rn(m1, m1, __dmul_rn(m0, m0)));
                const double inner = __fma_rn(qd2, m2, __fma_rn(qd1, m1, __dmul_rn(qd0, m0)));
                const unsigned long long kj =
                    ordd(__dadd_rn(__dsub_rn(sqnd, __dadd_rn(inner, inner)), sqm));
                rank += (kj < mk || (kj == mk && (unsigned)mj < mi)) ? 1 : 0;
            }
            if (c < C && rank < KK) emit_one(P, out, ws_idx, b, n, rank, mi);
        }
    }
}

// ==== gather v3 (UNCHANGED from round 9): dense 1 KB/wave stores, NT ====
__global__ __launch_bounds__(256) void gather_feats(const float* __restrict__ pf,
                                                    const int* __restrict__ ws_idx,
                                                    float* __restrict__ out1) {
    __shared__ float s_row[NN];

    const int blk = blockIdx.x;          // B * C * 8 = 4096
    const int nt = blk & 7;
    const int c  = (blk >> 3) & (CC - 1);
    const int b  = blk >> 10;
    const int tid = threadIdx.x;

    const float* __restrict__ row = pf + ((size_t)b * CC + c) * NN;
    {
        const f32x4* __restrict__ r4 = (const f32x4*)row;
        f32x4 a0 = r4[tid];
        f32x4 a1 = r4[tid + 256];
        ((f32x4*)s_row)[tid]       = a0;
        ((f32x4*)s_row)[tid + 256] = a1;
    }
    __syncthreads();

    const size_t cbase  = ((size_t)b * (2 * CC) + c) * NN * KK;   // (b,c,0,0)
    const size_t cbase2 = cbase + (size_t)CC * NN * KK;           // dup at c+128
    const int4* __restrict__ ibase =
        (const int4*)(ws_idx + (size_t)b * NN * KK);              // 4 int4 per n

#pragma unroll
    for (int task = 0; task < 4; ++task) {
        const int gid = task * 256 + tid;          // 0..1023 within tile
        const int n_sub = gid >> 2;
        const int qq = gid & 3;
        const int n = nt * 256 + n_sub;

        const int4 iv = ibase[n * 4 + qq];         // dense 1 KB/wave
        f32x4 f;
        f.x = s_row[iv.x]; f.y = s_row[iv.y]; f.z = s_row[iv.z]; f.w = s_row[iv.w];

        const size_t off = (size_t)n * KK + qq * 4;
        __builtin_nontemporal_store(f, (f32x4*)(out1 + cbase + off));
        __builtin_nontemporal_store(f, (f32x4*)(out1 + cbase2 + off));
    }
}

extern "C" void kernel_launch(void* const* d_in, const int* in_sizes, int n_in,
                              void* d_out, int out_size, void* d_ws, size_t ws_size,
                              hipStream_t stream) {
    (void)in_sizes; (void)n_in; (void)ws_size; (void)out_size;
    const float* pts = (const float*)d_in[0];
    const float* pf  = (const float*)d_in[1];
    float* out = (float*)d_out;
    int* ws_idx = (int*)d_ws;   // B*N*K int32 = 512 KB

    knn_kernel<<<(BB * NN) / 4, 256, 0, stream>>>(pts, out, ws_idx);
    gather_feats<<<BB * CC * 8, 256, 0, stream>>>(pf, ws_idx, out + OFF_GF);
}

// Round 11
// 49.337 us; speedup vs baseline: 2.7554x; 1.0447x over previous
//
#include <hip/hip_runtime.h>

#define BB 4
#define NN 2048
#define CC 128
#define KK 16
#define CAP 256   // fallback candidate capacity (common case C ~ 20)

typedef float f32x4 __attribute__((ext_vector_type(4)));

// fp32 element offsets within d_out
#define OFF_GF   ((size_t)BB * 3 * NN * KK)                 // grouped_features (B,256,N,K)
#define OFF_IDX  (OFF_GF + (size_t)BB * 2 * CC * NN * KK)   // idx_full (B,2,N,K)

__device__ __forceinline__ unsigned long long ordd(double d) {
    unsigned long long u = (unsigned long long)__double_as_longlong(d);
    return (u & 0x8000000000000000ull) ? ~u : (u | 0x8000000000000000ull);
}

__device__ __forceinline__ void emit_one(const float* __restrict__ P,
                                         float* __restrict__ out,
                                         int* __restrict__ ws_idx,
                                         int b, int n, int k, unsigned myidx) {
    const size_t nk = (size_t)NN * KK;
    const size_t base0 = ((size_t)(b * 3) * NN + n) * KK + k;
    out[base0]            = P[myidx];
    out[base0 + nk]       = P[NN + myidx];
    out[base0 + 2 * nk]   = P[2 * NN + myidx];
    const size_t base2 = ((size_t)(b * 2) * NN + n) * KK + k;
    out[OFF_IDX + base2]      = (float)b;
    out[OFF_IDX + base2 + nk] = (float)myidx;
    ws_idx[((size_t)b * NN + n) * KK + k] = (int)myidx;
}

// 4 waves/block, one query per wave. Single-scan fp32 screen: the 32 keys
// stay in registers (static-indexed, fully unrolled -> no scratch), so the
// compaction pass is register-only (no reload, no recompute).
__global__ __launch_bounds__(256) void knn_kernel(const float* __restrict__ pts,
                                                  float* __restrict__ out,
                                                  int* __restrict__ ws_idx) {
    __shared__ unsigned s_sid[4][CAP];

    const int w = threadIdx.x >> 6;
    const int lane = threadIdx.x & 63;
    const int q = blockIdx.x * 4 + w;
    const int b = q >> 11;
    const int n = q & (NN - 1);

    const float* __restrict__ P = pts + (size_t)b * 3 * NN;
    const f32x4* __restrict__ Px = (const f32x4*)P;
    const f32x4* __restrict__ Py = (const f32x4*)(P + NN);
    const f32x4* __restrict__ Pz = (const f32x4*)(P + 2 * NN);

    const float q0 = P[n], q1 = P[NN + n], q2 = P[2 * NN + n];
    const float sqn = fmaf(q2, q2, fmaf(q1, q1, q0 * q0));

    // ---- single scan: keys kept in 32 registers
    float key[32];
#pragma unroll
    for (int i = 0; i < 8; ++i) {
        const int v = i * 64 + lane;                  // float4 index
        const f32x4 mx = Px[v], my = Py[v], mz = Pz[v];
#define D2F(j) (sqn - 2.0f * fmaf(q2, mz[j], fmaf(q1, my[j], q0 * mx[j]))) \
               + fmaf(mz[j], mz[j], fmaf(my[j], my[j], mx[j] * mx[j]))
        key[i * 4 + 0] = D2F(0);
        key[i * 4 + 1] = D2F(1);
        key[i * 4 + 2] = D2F(2);
        key[i * 4 + 3] = D2F(3);
#undef D2F
    }
    float lmin = key[0];
#pragma unroll
    for (int i = 1; i < 32; ++i) lmin = key[i] < lmin ? key[i] : lmin;

    // ---- pivot: bitonic-sort the 64 lane-mins, take 16th smallest
    {
        float v = lmin;
#pragma unroll
        for (int k = 2; k <= 64; k <<= 1) {
#pragma unroll
            for (int j = k >> 1; j > 0; j >>= 1) {
                const float o = __shfl_xor(v, j, 64);
                const bool up = ((lane & k) == 0);
                const bool iAmLow = ((lane & j) == 0);
                const bool keepOther = (iAmLow == up) ? (o < v) : (o > v);
                v = keepOther ? o : v;
            }
        }
        lmin = __shfl(v, 15, 64);
    }
    const float piv = lmin + 2e-3f;   // fp32-vs-fp64 containment margin

    // ---- compaction pass: register compare + ballot prefix (no memory)
    const unsigned long long below = (1ull << lane) - 1ull;
    unsigned tot = 0;
#pragma unroll
    for (int i = 0; i < 8; ++i) {
#pragma unroll
        for (int j = 0; j < 4; ++j) {
            const bool cand = (key[i * 4 + j] <= piv);
            const unsigned long long mask = __ballot(cand);
            if (cand) {
                const unsigned pos = tot + (unsigned)__popcll(mask & below);
                if (pos < CAP) s_sid[w][pos] = (unsigned)(256 * i + 4 * lane + j);
            }
            tot += (unsigned)__popcll(mask);
        }
    }
    const int C = (int)(tot < CAP ? tot : CAP);
    __syncthreads();

    const double qd0 = (double)q0, qd1 = (double)q1, qd2 = (double)q2;
    const double sqnd = __fma_rn(qd2, qd2, __fma_rn(qd1, qd1, __dmul_rn(qd0, qd0)));

    if (C <= 64) {
        unsigned long long keyd = ~0ull;
        unsigned idx = 0xFFFFFFFFu;
        if (lane < C) {
            const int m = (int)s_sid[w][lane];
            const double m0 = (double)P[m], m1 = (double)P[NN + m], m2 = (double)P[2 * NN + m];
            const double sqm   = __fma_rn(m2, m2, __fma_rn(m1, m1, __dmul_rn(m0, m0)));
            const double inner = __fma_rn(qd2, m2, __fma_rn(qd1, m1, __dmul_rn(qd0, m0)));
            const double d2 = __dadd_rn(__dsub_rn(sqnd, __dadd_rn(inner, inner)), sqm);
            keyd = ordd(d2);
            idx = (unsigned)m;
        }
#pragma unroll
        for (int k = 2; k <= 64; k <<= 1) {
#pragma unroll
            for (int j = k >> 1; j > 0; j >>= 1) {
                const unsigned long long ok =
                    (unsigned long long)__shfl_xor((long long)keyd, j, 64);
                const unsigned oi = (unsigned)__shfl_xor((int)idx, j, 64);
                const bool up = ((lane & k) == 0);
                const bool iAmLow = ((lane & j) == 0);
                const bool oLess = (ok < keyd) || (ok == keyd && oi < idx);
                const bool keepOther = (iAmLow == up) ? oLess : !oLess;
                if (keepOther) { keyd = ok; idx = oi; }
            }
        }
        if (lane < KK) emit_one(P, out, ws_idx, b, n, lane, idx);
    } else {
        for (int cb = 0; cb < C; cb += 64) {
            const int c = cb + lane;
            unsigned long long mk = ~0ull;
            unsigned mi = 0xFFFFFFFFu;
            if (c < C) {
                const int m = (int)s_sid[w][c];
                const double m0 = (double)P[m], m1 = (double)P[NN + m], m2 = (double)P[2 * NN + m];
                const double sqm   = __fma_rn(m2, m2, __fma_rn(m1, m1, __dmul_rn(m0, m0)));
                const double inner = __fma_rn(qd2, m2, __fma_rn(qd1, m1, __dmul_rn(qd0, m0)));
                mk = ordd(__dadd_rn(__dsub_rn(sqnd, __dadd_rn(inner, inner)), sqm));
                mi = (unsigned)m;
            }
            int rank = 0;
            for (int j = 0; j < C; ++j) {
                const int mj = (int)s_sid[w][j];
                const double m0 = (double)P[mj], m1 = (double)P[NN + mj], m2 = (double)P[2 * NN + mj];
                const double sqm   = __fma_rn(m2, m2, __fma_rn(m1, m1, __dmul_rn(m0, m0)));
                const double inner = __fma_rn(qd2, m2, __fma_rn(qd1, m1, __dmul_rn(qd0, m0)));
                const unsigned long long kj =
                    ordd(__dadd_rn(__dsub_rn(sqnd, __dadd_rn(inner, inner)), sqm));
                rank += (kj < mk || (kj == mk && (unsigned)mj < mi)) ? 1 : 0;
            }
            if (c < C && rank < KK) emit_one(P, out, ws_idx, b, n, rank, mi);
        }
    }
}

// ==== gather v3 (UNCHANGED): dense 1 KB/wave stores, NT ====
__global__ __launch_bounds__(256) void gather_feats(const float* __restrict__ pf,
                                                    const int* __restrict__ ws_idx,
                                                    float* __restrict__ out1) {
    __shared__ float s_row[NN];

    const int blk = blockIdx.x;          // B * C * 8 = 4096
    const int nt = blk & 7;
    const int c  = (blk >> 3) & (CC - 1);
    const int b  = blk >> 10;
    const int tid = threadIdx.x;

    const float* __restrict__ row = pf + ((size_t)b * CC + c) * NN;
    {
        const f32x4* __restrict__ r4 = (const f32x4*)row;
        f32x4 a0 = r4[tid];
        f32x4 a1 = r4[tid + 256];
        ((f32x4*)s_row)[tid]       = a0;
        ((f32x4*)s_row)[tid + 256] = a1;
    }
    __syncthreads();

    const size_t cbase  = ((size_t)b * (2 * CC) + c) * NN * KK;   // (b,c,0,0)
    const size_t cbase2 = cbase + (size_t)CC * NN * KK;           // dup at c+128
    const int4* __restrict__ ibase =
        (const int4*)(ws_idx + (size_t)b * NN * KK);              // 4 int4 per n

#pragma unroll
    for (int task = 0; task < 4; ++task) {
        const int gid = task * 256 + tid;          // 0..1023 within tile
        const int n_sub = gid >> 2;
        const int qq = gid & 3;
        const int n = nt * 256 + n_sub;

        const int4 iv = ibase[n * 4 + qq];         // dense 1 KB/wave
        f32x4 f;
        f.x = s_row[iv.x]; f.y = s_row[iv.y]; f.z = s_row[iv.z]; f.w = s_row[iv.w];

        const size_t off = (size_t)n * KK + qq * 4;
        __builtin_nontemporal_store(f, (f32x4*)(out1 + cbase + off));
        __builtin_nontemporal_store(f, (f32x4*)(out1 + cbase2 + off));
    }
}

extern "C" void kernel_launch(void* const* d_in, const int* in_sizes, int n_in,
                              void* d_out, int out_size, void* d_ws, size_t ws_size,
                              hipStream_t stream) {
    (void)in_sizes; (void)n_in; (void)ws_size; (void)out_size;
    const float* pts = (const float*)d_in[0];
    const float* pf  = (const float*)d_in[1];
    float* out = (float*)d_out;
    int* ws_idx = (int*)d_ws;   // B*N*K int32 = 512 KB

    knn_kernel<<<(BB * NN) / 4, 256, 0, stream>>>(pts, out, ws_idx);
    gather_feats<<<BB * CC * 8, 256, 0, stream>>>(pf, ws_idx, out + OFF_GF);
}